// Round 12
// baseline (468.682 us; speedup 1.0000x reference)
//
#include <hip/hip_runtime.h>

#define N_NODES 50000
#define N_EDGES 800000
#define CH 128
#define N_GRAPHS 128
#define N_LAYERS 3
#define OUT_CH 16
#define BN_EPS 1e-5f
#define NSPLIT 16
#define NB 196            // dst>>8 buckets (256 dsts each)
#define BCAP 4608
#define EPB 4096
#define NTILES (N_NODES / 16)      // 3125 exact
#define SSTRIDE 20
#define QS  ((size_t)N_NODES * 16)   // quarter stride in dwords
#define QS2 ((size_t)N_NODES * 32)   // quarter stride in halfwords
// setup_kernel block partition
#define CB 6250            // cast blocks (1.6M float4 / 256)
#define SB 196             // starts blocks
#define PB 388             // prep blocks

typedef unsigned short ushort_t;
typedef __attribute__((ext_vector_type(8))) short bf16x8;
typedef __attribute__((ext_vector_type(4))) float f32x4;

__device__ inline ushort_t f2b(float f) {
    unsigned u = __float_as_uint(f);
    unsigned r = (u + 0x7fffu + ((u >> 16) & 1u)) >> 16;
    return (ushort_t)r;
}
__device__ inline float b2f(ushort_t b) { return __uint_as_float((unsigned)b << 16); }
__device__ inline float blo(unsigned u) { return __uint_as_float(u << 16); }
__device__ inline float bhi(unsigned u) { return __uint_as_float(u & 0xffff0000u); }

// ---------------- merged setup: cast(blocked) | starts+pooled-zero | prep ----------------
__global__ __launch_bounds__(256) void setup_kernel(
    const float4* __restrict__ x, ushort_t* __restrict__ xb, int* __restrict__ gcur,
    const int* __restrict__ batch, int* __restrict__ starts, float* __restrict__ pooled,
    const float* __restrict__ W1, const float* __restrict__ W2, ushort_t* __restrict__ Wt,
    const float* __restrict__ b1, const float* __restrict__ b2,
    const float* __restrict__ gamma, const float* __restrict__ beta,
    const float* __restrict__ mean, const float* __restrict__ var,
    float* __restrict__ scale, float* __restrict__ shift) {
    int bid = blockIdx.x, t = threadIdx.x;
    if (bid < CB) {
        // cast fp32 -> bf16 channel-blocked [4][N][32]; zero gcur
        int i = bid * 256 + t;
        if (i < NB) gcur[i] = 0;
        int node = i >> 5, v4 = i & 31;
        int q = v4 >> 3, co = (v4 & 7) * 4;
        float4 v = x[i];
        ushort4 o;
        o.x = f2b(v.x); o.y = f2b(v.y); o.z = f2b(v.z); o.w = f2b(v.w);
        *(ushort4*)&xb[(size_t)q * QS2 + (size_t)node * 32 + co] = o;
    } else if (bid < CB + SB) {
        int i = (bid - CB) * 256 + t;
        if (i < N_GRAPHS * CH) pooled[i] = 0.f;
        if (i >= N_NODES) return;
        int b = batch[i];
        if (i == 0) {
            for (int g = 0; g <= b; ++g) starts[g] = 0;
        } else {
            int pb = batch[i - 1];
            for (int g = pb + 1; g <= b; ++g) starts[g] = i;
        }
        if (i == N_NODES - 1) {
            for (int g = b + 1; g <= N_GRAPHS; ++g) starts[g] = N_NODES;
        }
    } else {
        int i = (bid - CB - SB) * 256 + t;
        if (i < 6 * CH * CH) {
            int mat = i >> 14, r = i & 16383;
            int j = r & 7, bb = r >> 3;
            int lane = bb & 63, cs = bb >> 6;
            int ct = cs >> 2, ks = cs & 3;
            int n = ct * 16 + (lane & 15);
            int k = ks * 32 + (lane >> 4) * 8 + j;
            const float* Wsrc = (mat < 3) ? (W1 + (size_t)mat * CH * CH)
                                          : (W2 + (size_t)(mat - 3) * CH * CH);
            Wt[i] = f2b(Wsrc[k * CH + n]);
        } else {
            int e = i - 6 * CH * CH;
            if (e >= 6 * CH) return;
            int mat = e / CH, c = e % CH;
            if (mat < 3) {
                scale[e] = 1.f;
                shift[e] = b1[mat * CH + c];
            } else {
                int l = mat - 3;
                float inv = gamma[l * CH + c] * rsqrtf(var[l * CH + c] + BN_EPS);
                scale[e] = inv;
                shift[e] = (b2[l * CH + c] - mean[l * CH + c]) * inv + beta[l * CH + c];
            }
        }
    }
}

// ---------------- edge binning: pack = src | (dst&255)<<16, bucket = dst>>8 ----------------
__global__ __launch_bounds__(256) void bin_kernel(const int* __restrict__ src,
                                                  const int* __restrict__ dst,
                                                  int* __restrict__ gcur,
                                                  unsigned* __restrict__ gbuck) {
    __shared__ int lcnt[256];
    __shared__ int lpref[256];
    __shared__ int lpos[NB];
    __shared__ int lbase[NB];
    __shared__ unsigned stage[EPB];
    __shared__ unsigned char sbk[EPB];
    int t = threadIdx.x;
    int e0 = blockIdx.x * EPB;
    int nloc = N_EDGES - e0; if (nloc > EPB) nloc = EPB;

    lcnt[t] = 0;
    __syncthreads();

    int2 ed[16];
    #pragma unroll
    for (int j = 0; j < 16; ++j) {
        int i = j * 256 + t;
        if (i < nloc) {
            ed[j].x = src[e0 + i];
            ed[j].y = dst[e0 + i];
            atomicAdd(&lcnt[ed[j].y >> 8], 1);
        } else ed[j].y = -1;
    }
    __syncthreads();
    int v = lcnt[t];
    lpref[t] = v;
    __syncthreads();
    for (int off = 1; off < 256; off <<= 1) {
        int y = (t >= off) ? lpref[t - off] : 0;
        __syncthreads();
        lpref[t] += y;
        __syncthreads();
    }
    int excl = lpref[t] - v;
    __syncthreads();
    lpref[t] = excl;
    if (t < NB) {
        lpos[t] = excl;
        lbase[t] = atomicAdd(&gcur[t], v);
    }
    __syncthreads();
    #pragma unroll
    for (int j = 0; j < 16; ++j) {
        if (ed[j].y >= 0) {
            int b = ed[j].y >> 8;
            int slot = atomicAdd(&lpos[b], 1);
            stage[slot] = (unsigned)ed[j].x | ((unsigned)(ed[j].y & 255) << 16);
            sbk[slot] = (unsigned char)b;
        }
    }
    __syncthreads();
    for (int i = t; i < nloc; i += 256) {
        int b = sbk[i];
        gbuck[(size_t)b * BCAP + lbase[b] + (i - lpref[b])] = stage[i];
    }
}

// ---------------- per-bucket sort to CSR slots; inline bucket scan; writes rowptr ----------
__global__ __launch_bounds__(256) void place_kernel(const int* __restrict__ gcur,
                                                    const unsigned* __restrict__ gbuck,
                                                    int* __restrict__ rowptr,
                                                    ushort_t* __restrict__ esrc) {
    __shared__ ushort_t ssrc[BCAP];
    __shared__ unsigned char sd[BCAP];
    __shared__ int outS[BCAP];
    __shared__ int cnt[256], pref[256], cur[256];
    __shared__ int sscan[256];
    int b = blockIdx.x, t = threadIdx.x;
    int gv = (t < NB) ? gcur[t] : 0;
    sscan[t] = gv;
    cnt[t] = 0;
    __syncthreads();
    for (int off = 1; off < 256; off <<= 1) {
        int y = (t >= off) ? sscan[t - off] : 0;
        __syncthreads();
        sscan[t] += y;
        __syncthreads();
    }
    int nb = gcur[b];
    int base = sscan[b] - nb;
    for (int i = t; i < nb; i += 256) {
        unsigned p = gbuck[(size_t)b * BCAP + i];
        ssrc[i] = (ushort_t)(p & 0xffffu);
        int dl = (p >> 16) & 0xff;
        sd[i] = (unsigned char)dl;
        atomicAdd(&cnt[dl], 1);
    }
    __syncthreads();
    int v = cnt[t];
    pref[t] = v;
    __syncthreads();
    for (int off = 1; off < 256; off <<= 1) {
        int y = (t >= off) ? pref[t - off] : 0;
        __syncthreads();
        pref[t] += y;
        __syncthreads();
    }
    int excl = pref[t] - v;
    __syncthreads();
    pref[t] = excl;
    cur[t] = 0;
    int idx = (b << 8) + t;
    if (idx < N_NODES) rowptr[idx] = base + excl;
    if (b == NB - 1 && t == 0) rowptr[N_NODES] = N_EDGES;
    __syncthreads();
    for (int i = t; i < nb; i += 256) {
        int dl = sd[i];
        int p = pref[dl] + atomicAdd(&cur[dl], 1);
        outS[p] = ssrc[i];
    }
    __syncthreads();
    for (int i = t; i < nb; i += 256)
        esrc[base + i] = (ushort_t)outS[i];
}

// ---------------- quarter aggregation: wave/node, 4 edges x 16 dwords per instr ----------
// One launch per quarter: the 3.2 MB slice stays L2-resident per XCD.
// z nontemporal (don't pollute L2); esrc nontemporal.
__global__ __launch_bounds__(256) void aggq_kernel(const unsigned* __restrict__ hq,
                                                   const int* __restrict__ rowptr,
                                                   const ushort_t* __restrict__ esrc,
                                                   unsigned* __restrict__ zq) {
    int wid = (blockIdx.x * 256 + threadIdx.x) >> 6;
    int lane = threadIdx.x & 63;
    if (wid >= N_NODES) return;
    int slot = lane >> 4, ld = lane & 15;
    float ax = 0.f, ay = 0.f;
    int e = rowptr[wid], end = rowptr[wid + 1];
    for (; e + 16 <= end; e += 16) {
        unsigned u[4];
        #pragma unroll
        for (int it = 0; it < 4; ++it) {
            int s = __builtin_nontemporal_load(&esrc[e + it * 4 + slot]);
            u[it] = hq[(unsigned)s * 16 + ld];
        }
        #pragma unroll
        for (int it = 0; it < 4; ++it) { ax += blo(u[it]); ay += bhi(u[it]); }
    }
    for (; e + 4 <= end; e += 4) {
        int s = __builtin_nontemporal_load(&esrc[e + slot]);
        unsigned u = hq[(unsigned)s * 16 + ld];
        ax += blo(u); ay += bhi(u);
    }
    if (e < end) {
        int m = end - e;
        int s = __builtin_nontemporal_load(&esrc[(slot < m) ? e + slot : e]);
        unsigned u = hq[(unsigned)s * 16 + ld];
        if (slot < m) { ax += blo(u); ay += bhi(u); }
    }
    ax += __shfl_xor(ax, 16); ax += __shfl_xor(ax, 32);
    ay += __shfl_xor(ay, 16); ay += __shfl_xor(ay, 32);
    if (lane < 16) {
        unsigned self = hq[(unsigned)wid * 16 + lane];
        float fx = ax + blo(self), fy = ay + bhi(self);
        unsigned pk = ((unsigned)f2b(fy) << 16) | (unsigned)f2b(fx);
        __builtin_nontemporal_store(pk, &zq[(unsigned)wid * 16 + lane]);
    }
}

// ---------------- fused MLP (conflict-free), blocked I/O layout ----------------
__global__ __launch_bounds__(512) void mlp_kernel(const ushort_t* __restrict__ A,
                                                  const ushort_t* __restrict__ Wf1,
                                                  const ushort_t* __restrict__ Wf2,
                                                  const float* __restrict__ shift1,
                                                  const float* __restrict__ scale2,
                                                  const float* __restrict__ shift2,
                                                  ushort_t* __restrict__ Out) {
    __shared__ ushort_t sW1[CH * CH];
    __shared__ ushort_t sW2[CH * CH];
    __shared__ ushort_t sS[8][CH * SSTRIDE];

    int t = threadIdx.x;
    int wave = t >> 6, lane = t & 63;
    int quad = lane >> 4, l16 = lane & 15;

    {
        const uint4* g1 = (const uint4*)Wf1;
        const uint4* g2 = (const uint4*)Wf2;
        uint4* s1 = (uint4*)sW1;
        uint4* s2 = (uint4*)sW2;
        for (int i = t; i < 2048; i += 512) { s1[i] = g1[i]; s2[i] = g2[i]; }
    }
    __syncthreads();

    const bf16x8* w1f = (const bf16x8*)sW1;
    const bf16x8* w2f = (const bf16x8*)sW2;
    int wg = blockIdx.x * 8 + wave;

    for (int it = 0; it < 2; ++it) {
        int tile = wg + 2048 * it;
        if (tile >= NTILES) break;
        int arow = tile * 16 + l16;

        // A-frag K-step ks == channel quarter ks in blocked layout
        bf16x8 af[4];
        #pragma unroll
        for (int ks = 0; ks < 4; ++ks)
            af[ks] = *(const bf16x8*)(A + (size_t)ks * QS2 + (size_t)arow * 32 + quad * 8);

        f32x4 acc[8];
        #pragma unroll
        for (int ct = 0; ct < 8; ++ct) acc[ct] = (f32x4){0.f, 0.f, 0.f, 0.f};
        #pragma unroll
        for (int ct = 0; ct < 8; ++ct)
            #pragma unroll
            for (int ks = 0; ks < 4; ++ks)
                acc[ct] = __builtin_amdgcn_mfma_f32_16x16x32_bf16(
                    af[ks], w1f[(ct * 4 + ks) * 64 + lane], acc[ct], 0, 0, 0);

        #pragma unroll
        for (int ct = 0; ct < 8; ++ct) {
            int k = ct * 16 + l16;
            float sh = shift1[k];
            uint2 p;
            p.x = ((unsigned)f2b(fmaxf(acc[ct][1] + sh, 0.f)) << 16)
                |  (unsigned)f2b(fmaxf(acc[ct][0] + sh, 0.f));
            p.y = ((unsigned)f2b(fmaxf(acc[ct][3] + sh, 0.f)) << 16)
                |  (unsigned)f2b(fmaxf(acc[ct][2] + sh, 0.f));
            *(uint2*)&sS[wave][k * SSTRIDE + quad * 4] = p;
        }

        bf16x8 af2[4];
        #pragma unroll
        for (int ks = 0; ks < 4; ++ks)
            #pragma unroll
            for (int j = 0; j < 8; ++j)
                af2[ks][j] = (short)sS[wave][(ks * 32 + quad * 8 + j) * SSTRIDE + l16];

        f32x4 acc2[8];
        #pragma unroll
        for (int ct = 0; ct < 8; ++ct) acc2[ct] = (f32x4){0.f, 0.f, 0.f, 0.f};
        #pragma unroll
        for (int ct = 0; ct < 8; ++ct)
            #pragma unroll
            for (int ks = 0; ks < 4; ++ks)
                acc2[ct] = __builtin_amdgcn_mfma_f32_16x16x32_bf16(
                    af2[ks], w2f[(ct * 4 + ks) * 64 + lane], acc2[ct], 0, 0, 0);

        int row0 = tile * 16;
        #pragma unroll
        for (int ct = 0; ct < 8; ++ct) {
            int col = ct * 16 + l16;
            float sc = scale2[col], sh = shift2[col];
            int qc = col >> 5, co = col & 31;
            #pragma unroll
            for (int r = 0; r < 4; ++r) {
                int row = row0 + quad * 4 + r;
                Out[(size_t)qc * QS2 + (size_t)row * 32 + co] =
                    f2b(fmaxf(acc2[ct][r] * sc + sh, 0.f));
            }
        }
    }
}

// ---------------- pooling (blocked dword reads, 16 splits) + classifier ----------------
__global__ __launch_bounds__(64) void pool_kernel(const unsigned* __restrict__ h2,
                                                  const int* __restrict__ starts,
                                                  float* __restrict__ pooled) {
    int g = blockIdx.x >> 4, s = blockIdx.x & 15;
    int c = threadIdx.x;            // 0..63: q = c>>4, dword ld = c&15
    int q = c >> 4, ld = c & 15;
    const unsigned* hq = h2 + (size_t)q * QS;
    int beg = starts[g], end = starts[g + 1];
    float s0 = 0.f, s1 = 0.f;
    for (int n = beg + s; n < end; n += NSPLIT) {
        unsigned u = hq[(size_t)n * 16 + ld];
        s0 += blo(u); s1 += bhi(u);
    }
    int ch = q * 32 + 2 * ld;
    atomicAdd(&pooled[g * CH + ch], s0);
    atomicAdd(&pooled[g * CH + ch + 1], s1);
}

__global__ __launch_bounds__(256) void cls_kernel(const float* __restrict__ pooled,
                                                  const float* __restrict__ Wc,
                                                  const float* __restrict__ bc,
                                                  float* __restrict__ out) {
    int i = blockIdx.x * blockDim.x + threadIdx.x;
    if (i >= N_GRAPHS * OUT_CH) return;
    int g = i / OUT_CH, o = i % OUT_CH;
    float s = bc[o];
    for (int k = 0; k < CH; ++k) s += pooled[g * CH + k] * Wc[k * OUT_CH + o];
    out[i] = s;
}

// ---------------- launch ----------------
extern "C" void kernel_launch(void* const* d_in, const int* in_sizes, int n_in,
                              void* d_out, int out_size, void* d_ws, size_t ws_size,
                              hipStream_t stream) {
    const float* x     = (const float*)d_in[0];
    const int*   eidx  = (const int*)d_in[1];
    const int*   batch = (const int*)d_in[2];
    const float* W1    = (const float*)d_in[3];
    const float* b1    = (const float*)d_in[4];
    const float* W2    = (const float*)d_in[5];
    const float* b2    = (const float*)d_in[6];
    const float* gamma = (const float*)d_in[7];
    const float* beta  = (const float*)d_in[8];
    const float* mean  = (const float*)d_in[9];
    const float* var   = (const float*)d_in[10];
    const float* Wc    = (const float*)d_in[11];
    const float* bc    = (const float*)d_in[12];
    float* out = (float*)d_out;

    const int* src = eidx;
    const int* dst = eidx + N_EDGES;

    char* w = (char*)d_ws;
    size_t off = 0;
    auto alloc = [&](size_t bytes) { void* p = w + off; off += (bytes + 255) & ~(size_t)255; return p; };
    int*      gcur   = (int*)alloc(NB * 4);
    unsigned* gbuck  = (unsigned*)alloc((size_t)NB * BCAP * 4);
    int*      rowptr = (int*)alloc((N_NODES + 1) * 4);
    ushort_t* esrc   = (ushort_t*)alloc(N_EDGES * 2);
    int*      starts = (int*)alloc((N_GRAPHS + 1) * 4);
    ushort_t* Bh     = (ushort_t*)alloc((size_t)N_NODES * CH * 2);
    ushort_t* Bz     = (ushort_t*)alloc((size_t)N_NODES * CH * 2);
    ushort_t* Wt     = (ushort_t*)alloc((size_t)6 * CH * CH * 2);
    float*    scale  = (float*)alloc(6 * CH * 4);
    float*    shift  = (float*)alloc(6 * CH * 4);
    float*    pooled = (float*)alloc(N_GRAPHS * CH * 4);
    (void)ws_size; (void)n_in; (void)in_sizes; (void)out_size;

    setup_kernel<<<CB + SB + PB, 256, 0, stream>>>(
        (const float4*)x, Bh, gcur,
        batch, starts, pooled,
        W1, W2, Wt, b1, b2, gamma, beta, mean, var, scale, shift);
    bin_kernel<<<(N_EDGES + EPB - 1) / EPB, 256, 0, stream>>>(src, dst, gcur, gbuck);
    place_kernel<<<NB, 256, 0, stream>>>(gcur, gbuck, rowptr, esrc);

    const int aggq_grid = (N_NODES + 3) / 4;   // wave/node, 4 waves/block

    ushort_t* hbuf = Bh;
    ushort_t* zbuf = Bz;
    for (int i = 0; i < N_LAYERS; ++i) {
        // 4 quarter passes, separate launches -> temporal L2 separation
        for (int q = 0; q < 4; ++q) {
            aggq_kernel<<<aggq_grid, 256, 0, stream>>>(
                (const unsigned*)(hbuf + (size_t)q * QS2), rowptr, esrc,
                (unsigned*)(zbuf + (size_t)q * QS2));
        }
        mlp_kernel<<<256, 512, 0, stream>>>(zbuf,
                                            Wt + (size_t)i * CH * CH,
                                            Wt + (size_t)(3 + i) * CH * CH,
                                            shift + i * CH,
                                            scale + (3 + i) * CH,
                                            shift + (3 + i) * CH,
                                            hbuf);
        // note: mlp reads zbuf and writes hbuf (ping-pong not needed; z is scratch)
    }

    pool_kernel<<<N_GRAPHS * NSPLIT, 64, 0, stream>>>((const unsigned*)Bh, starts, pooled);
    cls_kernel<<<(N_GRAPHS * OUT_CH + 255) / 256, 256, 0, stream>>>(pooled, Wc, bc, out);
}

// Round 13
// 319.132 us; speedup vs baseline: 1.4686x; 1.4686x over previous
//
#include <hip/hip_runtime.h>

#define N_NODES 50000
#define N_EDGES 800000
#define CH 128
#define N_GRAPHS 128
#define N_LAYERS 3
#define OUT_CH 16
#define BN_EPS 1e-5f
#define NSPLIT 16
#define NB 196            // dst>>8 buckets (256 dsts each)
#define BCAP 4608
#define EPB 4096
#define NTILES (N_NODES / 16)      // 3125 exact
#define SSTRIDE 20
// setup_kernel block partition
#define CB 6250            // cast blocks (1.6M float4 / 256)
#define SB 196             // starts blocks
#define PB 388             // prep blocks

typedef unsigned short ushort_t;
typedef __attribute__((ext_vector_type(8))) short bf16x8;
typedef __attribute__((ext_vector_type(4))) float f32x4;

__device__ inline ushort_t f2b(float f) {
    unsigned u = __float_as_uint(f);
    unsigned r = (u + 0x7fffu + ((u >> 16) & 1u)) >> 16;
    return (ushort_t)r;
}
__device__ inline float b2f(ushort_t b) { return __uint_as_float((unsigned)b << 16); }
__device__ inline float blo(unsigned u) { return __uint_as_float(u << 16); }
__device__ inline float bhi(unsigned u) { return __uint_as_float(u & 0xffff0000u); }

// ---------------- merged setup: cast | starts+pooled-zero | weight/epilogue prep ----------
__global__ __launch_bounds__(256) void setup_kernel(
    const float4* __restrict__ x, ushort4* __restrict__ xb, int* __restrict__ gcur,
    const int* __restrict__ batch, int* __restrict__ starts, float* __restrict__ pooled,
    const float* __restrict__ W1, const float* __restrict__ W2, ushort_t* __restrict__ Wt,
    const float* __restrict__ b1, const float* __restrict__ b2,
    const float* __restrict__ gamma, const float* __restrict__ beta,
    const float* __restrict__ mean, const float* __restrict__ var,
    float* __restrict__ scale, float* __restrict__ shift) {
    int bid = blockIdx.x, t = threadIdx.x;
    if (bid < CB) {
        // ---- cast fp32 -> bf16 flat [N][128]; zero gcur ----
        int i = bid * 256 + t;
        if (i < NB) gcur[i] = 0;
        float4 v = x[i];               // CB*256 == n4 exactly
        ushort4 o;
        o.x = f2b(v.x); o.y = f2b(v.y); o.z = f2b(v.z); o.w = f2b(v.w);
        xb[i] = o;
    } else if (bid < CB + SB) {
        // ---- graph starts from sorted batch; zero pooled ----
        int i = (bid - CB) * 256 + t;
        if (i < N_GRAPHS * CH) pooled[i] = 0.f;
        if (i >= N_NODES) return;
        int b = batch[i];
        if (i == 0) {
            for (int g = 0; g <= b; ++g) starts[g] = 0;
        } else {
            int pb = batch[i - 1];
            for (int g = pb + 1; g <= b; ++g) starts[g] = i;
        }
        if (i == N_NODES - 1) {
            for (int g = b + 1; g <= N_GRAPHS; ++g) starts[g] = N_NODES;
        }
    } else {
        // ---- weight fragments [ct][ks][lane][j] + scale/shift ----
        int i = (bid - CB - SB) * 256 + t;
        if (i < 6 * CH * CH) {
            int mat = i >> 14, r = i & 16383;
            int j = r & 7, bb = r >> 3;
            int lane = bb & 63, cs = bb >> 6;
            int ct = cs >> 2, ks = cs & 3;
            int n = ct * 16 + (lane & 15);
            int k = ks * 32 + (lane >> 4) * 8 + j;
            const float* Wsrc = (mat < 3) ? (W1 + (size_t)mat * CH * CH)
                                          : (W2 + (size_t)(mat - 3) * CH * CH);
            Wt[i] = f2b(Wsrc[k * CH + n]);
        } else {
            int e = i - 6 * CH * CH;
            if (e >= 6 * CH) return;
            int mat = e / CH, c = e % CH;
            if (mat < 3) {
                scale[e] = 1.f;
                shift[e] = b1[mat * CH + c];
            } else {
                int l = mat - 3;
                float inv = gamma[l * CH + c] * rsqrtf(var[l * CH + c] + BN_EPS);
                scale[e] = inv;
                shift[e] = (b2[l * CH + c] - mean[l * CH + c]) * inv + beta[l * CH + c];
            }
        }
    }
}

// ---------------- edge binning: pack = src | (dst&255)<<16, bucket = dst>>8 ----------------
__global__ __launch_bounds__(256) void bin_kernel(const int* __restrict__ src,
                                                  const int* __restrict__ dst,
                                                  int* __restrict__ gcur,
                                                  unsigned* __restrict__ gbuck) {
    __shared__ int lcnt[256];
    __shared__ int lpref[256];
    __shared__ int lpos[NB];
    __shared__ int lbase[NB];
    __shared__ unsigned stage[EPB];
    __shared__ unsigned char sbk[EPB];
    int t = threadIdx.x;
    int e0 = blockIdx.x * EPB;
    int nloc = N_EDGES - e0; if (nloc > EPB) nloc = EPB;

    lcnt[t] = 0;
    __syncthreads();

    int2 ed[16];
    #pragma unroll
    for (int j = 0; j < 16; ++j) {
        int i = j * 256 + t;
        if (i < nloc) {
            ed[j].x = src[e0 + i];
            ed[j].y = dst[e0 + i];
            atomicAdd(&lcnt[ed[j].y >> 8], 1);
        } else ed[j].y = -1;
    }
    __syncthreads();
    int v = lcnt[t];
    lpref[t] = v;
    __syncthreads();
    for (int off = 1; off < 256; off <<= 1) {
        int y = (t >= off) ? lpref[t - off] : 0;
        __syncthreads();
        lpref[t] += y;
        __syncthreads();
    }
    int excl = lpref[t] - v;
    __syncthreads();
    lpref[t] = excl;
    if (t < NB) {
        lpos[t] = excl;
        lbase[t] = atomicAdd(&gcur[t], v);
    }
    __syncthreads();
    #pragma unroll
    for (int j = 0; j < 16; ++j) {
        if (ed[j].y >= 0) {
            int b = ed[j].y >> 8;
            int slot = atomicAdd(&lpos[b], 1);
            stage[slot] = (unsigned)ed[j].x | ((unsigned)(ed[j].y & 255) << 16);
            sbk[slot] = (unsigned char)b;
        }
    }
    __syncthreads();
    for (int i = t; i < nloc; i += 256) {
        int b = sbk[i];
        gbuck[(size_t)b * BCAP + lbase[b] + (i - lpref[b])] = stage[i];
    }
}

// ---------------- per-bucket sort to CSR slots; inline bucket scan; writes rowptr ----------
__global__ __launch_bounds__(256) void place_kernel(const int* __restrict__ gcur,
                                                    const unsigned* __restrict__ gbuck,
                                                    int* __restrict__ rowptr,
                                                    ushort_t* __restrict__ esrc) {
    __shared__ ushort_t ssrc[BCAP];
    __shared__ unsigned char sd[BCAP];
    __shared__ int outS[BCAP];
    __shared__ int cnt[256], pref[256], cur[256];
    __shared__ int sscan[256];
    int b = blockIdx.x, t = threadIdx.x;
    // inline exclusive scan over all bucket sizes -> this bucket's base
    int gv = (t < NB) ? gcur[t] : 0;
    sscan[t] = gv;
    cnt[t] = 0;
    __syncthreads();
    for (int off = 1; off < 256; off <<= 1) {
        int y = (t >= off) ? sscan[t - off] : 0;
        __syncthreads();
        sscan[t] += y;
        __syncthreads();
    }
    int nb = gcur[b];
    int base = sscan[b] - nb;   // exclusive prefix
    for (int i = t; i < nb; i += 256) {
        unsigned p = gbuck[(size_t)b * BCAP + i];
        ssrc[i] = (ushort_t)(p & 0xffffu);
        int dl = (p >> 16) & 0xff;
        sd[i] = (unsigned char)dl;
        atomicAdd(&cnt[dl], 1);
    }
    __syncthreads();
    int v = cnt[t];
    pref[t] = v;
    __syncthreads();
    for (int off = 1; off < 256; off <<= 1) {
        int y = (t >= off) ? pref[t - off] : 0;
        __syncthreads();
        pref[t] += y;
        __syncthreads();
    }
    int excl = pref[t] - v;
    __syncthreads();
    pref[t] = excl;
    cur[t] = 0;
    int idx = (b << 8) + t;
    if (idx < N_NODES) rowptr[idx] = base + excl;
    if (b == NB - 1 && t == 0) rowptr[N_NODES] = N_EDGES;
    __syncthreads();
    for (int i = t; i < nb; i += 256) {
        int dl = sd[i];
        int p = pref[dl] + atomicAdd(&cur[dl], 1);
        outS[p] = ssrc[i];
    }
    __syncthreads();
    for (int i = t; i < nb; i += 256)
        esrc[base + i] = (ushort_t)outS[i];
}

// ---------------- aggregation: pull, wave/node, 16-deep gather unroll, u16 indices --------
// Index stream read as wave-uniform uint4 (8 packed u16 per load).
__global__ __launch_bounds__(256) void agg_kernel(const unsigned* __restrict__ h2,
                                                  const int* __restrict__ rowptr,
                                                  const ushort_t* __restrict__ esrc,
                                                  unsigned* __restrict__ z2) {
    int wid = (blockIdx.x * 256 + threadIdx.x) >> 6;
    int lane = threadIdx.x & 63;
    if (wid >= N_NODES) return;
    unsigned self = h2[(size_t)wid * 64 + lane];
    float ax = blo(self), ay = bhi(self);
    int e = rowptr[wid], end = rowptr[wid + 1];
    // head: scalar until e is 8-aligned (uint4 alignment for u16 stream)
    for (; e < end && (e & 7); ++e) {
        unsigned u = h2[(size_t)esrc[e] * 64 + lane];
        ax += blo(u); ay += bhi(u);
    }
    for (; e + 16 <= end; e += 16) {
        uint4 pa = *(const uint4*)&esrc[e];
        uint4 pb = *(const uint4*)&esrc[e + 8];
        unsigned u[16];
        u[0]  = h2[(size_t)(pa.x & 0xffffu) * 64 + lane];
        u[1]  = h2[(size_t)(pa.x >> 16)     * 64 + lane];
        u[2]  = h2[(size_t)(pa.y & 0xffffu) * 64 + lane];
        u[3]  = h2[(size_t)(pa.y >> 16)     * 64 + lane];
        u[4]  = h2[(size_t)(pa.z & 0xffffu) * 64 + lane];
        u[5]  = h2[(size_t)(pa.z >> 16)     * 64 + lane];
        u[6]  = h2[(size_t)(pa.w & 0xffffu) * 64 + lane];
        u[7]  = h2[(size_t)(pa.w >> 16)     * 64 + lane];
        u[8]  = h2[(size_t)(pb.x & 0xffffu) * 64 + lane];
        u[9]  = h2[(size_t)(pb.x >> 16)     * 64 + lane];
        u[10] = h2[(size_t)(pb.y & 0xffffu) * 64 + lane];
        u[11] = h2[(size_t)(pb.y >> 16)     * 64 + lane];
        u[12] = h2[(size_t)(pb.z & 0xffffu) * 64 + lane];
        u[13] = h2[(size_t)(pb.z >> 16)     * 64 + lane];
        u[14] = h2[(size_t)(pb.w & 0xffffu) * 64 + lane];
        u[15] = h2[(size_t)(pb.w >> 16)     * 64 + lane];
        #pragma unroll
        for (int j = 0; j < 16; ++j) { ax += blo(u[j]); ay += bhi(u[j]); }
    }
    for (; e + 8 <= end; e += 8) {
        uint4 pa = *(const uint4*)&esrc[e];
        unsigned u[8];
        u[0] = h2[(size_t)(pa.x & 0xffffu) * 64 + lane];
        u[1] = h2[(size_t)(pa.x >> 16)     * 64 + lane];
        u[2] = h2[(size_t)(pa.y & 0xffffu) * 64 + lane];
        u[3] = h2[(size_t)(pa.y >> 16)     * 64 + lane];
        u[4] = h2[(size_t)(pa.z & 0xffffu) * 64 + lane];
        u[5] = h2[(size_t)(pa.z >> 16)     * 64 + lane];
        u[6] = h2[(size_t)(pa.w & 0xffffu) * 64 + lane];
        u[7] = h2[(size_t)(pa.w >> 16)     * 64 + lane];
        #pragma unroll
        for (int j = 0; j < 8; ++j) { ax += blo(u[j]); ay += bhi(u[j]); }
    }
    for (; e < end; ++e) {
        unsigned u = h2[(size_t)esrc[e] * 64 + lane];
        ax += blo(u); ay += bhi(u);
    }
    z2[(size_t)wid * 64 + lane] = ((unsigned)f2b(ay) << 16) | (unsigned)f2b(ax);
}

// ---------------- fused MLP (R8 conflict-free form) ----------------
__global__ __launch_bounds__(512) void mlp_kernel(const ushort_t* __restrict__ A,
                                                  const ushort_t* __restrict__ Wf1,
                                                  const ushort_t* __restrict__ Wf2,
                                                  const float* __restrict__ shift1,
                                                  const float* __restrict__ scale2,
                                                  const float* __restrict__ shift2,
                                                  ushort_t* __restrict__ Out) {
    __shared__ ushort_t sW1[CH * CH];
    __shared__ ushort_t sW2[CH * CH];
    __shared__ ushort_t sS[8][CH * SSTRIDE];

    int t = threadIdx.x;
    int wave = t >> 6, lane = t & 63;
    int quad = lane >> 4, l16 = lane & 15;

    {
        const uint4* g1 = (const uint4*)Wf1;
        const uint4* g2 = (const uint4*)Wf2;
        uint4* s1 = (uint4*)sW1;
        uint4* s2 = (uint4*)sW2;
        for (int i = t; i < 2048; i += 512) { s1[i] = g1[i]; s2[i] = g2[i]; }
    }
    __syncthreads();

    const bf16x8* w1f = (const bf16x8*)sW1;
    const bf16x8* w2f = (const bf16x8*)sW2;
    int wg = blockIdx.x * 8 + wave;

    for (int it = 0; it < 2; ++it) {
        int tile = wg + 2048 * it;
        if (tile >= NTILES) break;
        int arow = tile * 16 + l16;

        bf16x8 af[4];
        #pragma unroll
        for (int ks = 0; ks < 4; ++ks)
            af[ks] = *(const bf16x8*)(A + (size_t)arow * CH + ks * 32 + quad * 8);

        f32x4 acc[8];
        #pragma unroll
        for (int ct = 0; ct < 8; ++ct) acc[ct] = (f32x4){0.f, 0.f, 0.f, 0.f};
        #pragma unroll
        for (int ct = 0; ct < 8; ++ct)
            #pragma unroll
            for (int ks = 0; ks < 4; ++ks)
                acc[ct] = __builtin_amdgcn_mfma_f32_16x16x32_bf16(
                    af[ks], w1f[(ct * 4 + ks) * 64 + lane], acc[ct], 0, 0, 0);

        #pragma unroll
        for (int ct = 0; ct < 8; ++ct) {
            int k = ct * 16 + l16;
            float sh = shift1[k];
            uint2 p;
            p.x = ((unsigned)f2b(fmaxf(acc[ct][1] + sh, 0.f)) << 16)
                |  (unsigned)f2b(fmaxf(acc[ct][0] + sh, 0.f));
            p.y = ((unsigned)f2b(fmaxf(acc[ct][3] + sh, 0.f)) << 16)
                |  (unsigned)f2b(fmaxf(acc[ct][2] + sh, 0.f));
            *(uint2*)&sS[wave][k * SSTRIDE + quad * 4] = p;
        }

        bf16x8 af2[4];
        #pragma unroll
        for (int ks = 0; ks < 4; ++ks)
            #pragma unroll
            for (int j = 0; j < 8; ++j)
                af2[ks][j] = (short)sS[wave][(ks * 32 + quad * 8 + j) * SSTRIDE + l16];

        f32x4 acc2[8];
        #pragma unroll
        for (int ct = 0; ct < 8; ++ct) acc2[ct] = (f32x4){0.f, 0.f, 0.f, 0.f};
        #pragma unroll
        for (int ct = 0; ct < 8; ++ct)
            #pragma unroll
            for (int ks = 0; ks < 4; ++ks)
                acc2[ct] = __builtin_amdgcn_mfma_f32_16x16x32_bf16(
                    af2[ks], w2f[(ct * 4 + ks) * 64 + lane], acc2[ct], 0, 0, 0);

        int row0 = tile * 16;
        #pragma unroll
        for (int ct = 0; ct < 8; ++ct) {
            int col = ct * 16 + l16;
            float sc = scale2[col], sh = shift2[col];
            #pragma unroll
            for (int r = 0; r < 4; ++r) {
                int row = row0 + quad * 4 + r;
                Out[(size_t)row * CH + col] = f2b(fmaxf(acc2[ct][r] * sc + sh, 0.f));
            }
        }
    }
}

// ---------------- pooling (dword reads, 16 splits) + classifier ----------------
__global__ __launch_bounds__(64) void pool_kernel(const unsigned* __restrict__ h2,
                                                  const int* __restrict__ starts,
                                                  float* __restrict__ pooled) {
    int g = blockIdx.x >> 4, s = blockIdx.x & 15;
    int c = threadIdx.x;
    int beg = starts[g], end = starts[g + 1];
    float s0 = 0.f, s1 = 0.f;
    for (int n = beg + s; n < end; n += NSPLIT) {
        unsigned u = h2[(size_t)n * 64 + c];
        s0 += blo(u); s1 += bhi(u);
    }
    atomicAdd(&pooled[g * CH + 2 * c], s0);
    atomicAdd(&pooled[g * CH + 2 * c + 1], s1);
}

__global__ __launch_bounds__(256) void cls_kernel(const float* __restrict__ pooled,
                                                  const float* __restrict__ Wc,
                                                  const float* __restrict__ bc,
                                                  float* __restrict__ out) {
    int i = blockIdx.x * blockDim.x + threadIdx.x;
    if (i >= N_GRAPHS * OUT_CH) return;
    int g = i / OUT_CH, o = i % OUT_CH;
    float s = bc[o];
    for (int k = 0; k < CH; ++k) s += pooled[g * CH + k] * Wc[k * OUT_CH + o];
    out[i] = s;
}

// ---------------- launch ----------------
extern "C" void kernel_launch(void* const* d_in, const int* in_sizes, int n_in,
                              void* d_out, int out_size, void* d_ws, size_t ws_size,
                              hipStream_t stream) {
    const float* x     = (const float*)d_in[0];
    const int*   eidx  = (const int*)d_in[1];
    const int*   batch = (const int*)d_in[2];
    const float* W1    = (const float*)d_in[3];
    const float* b1    = (const float*)d_in[4];
    const float* W2    = (const float*)d_in[5];
    const float* b2    = (const float*)d_in[6];
    const float* gamma = (const float*)d_in[7];
    const float* beta  = (const float*)d_in[8];
    const float* mean  = (const float*)d_in[9];
    const float* var   = (const float*)d_in[10];
    const float* Wc    = (const float*)d_in[11];
    const float* bc    = (const float*)d_in[12];
    float* out = (float*)d_out;

    const int* src = eidx;
    const int* dst = eidx + N_EDGES;

    char* w = (char*)d_ws;
    size_t off = 0;
    auto alloc = [&](size_t bytes) { void* p = w + off; off += (bytes + 255) & ~(size_t)255; return p; };
    int*      gcur   = (int*)alloc(NB * 4);
    unsigned* gbuck  = (unsigned*)alloc((size_t)NB * BCAP * 4);
    int*      rowptr = (int*)alloc((N_NODES + 1) * 4);
    ushort_t* esrc   = (ushort_t*)alloc(N_EDGES * 2);
    int*      starts = (int*)alloc((N_GRAPHS + 1) * 4);
    ushort_t* Bh     = (ushort_t*)alloc((size_t)N_NODES * CH * 2);
    ushort_t* Bz     = (ushort_t*)alloc((size_t)N_NODES * CH * 2);
    ushort_t* Wt     = (ushort_t*)alloc((size_t)6 * CH * CH * 2);
    float*    scale  = (float*)alloc(6 * CH * 4);
    float*    shift  = (float*)alloc(6 * CH * 4);
    float*    pooled = (float*)alloc(N_GRAPHS * CH * 4);
    (void)ws_size; (void)n_in; (void)in_sizes; (void)out_size;

    setup_kernel<<<CB + SB + PB, 256, 0, stream>>>(
        (const float4*)x, (ushort4*)Bh, gcur,
        batch, starts, pooled,
        W1, W2, Wt, b1, b2, gamma, beta, mean, var, scale, shift);
    bin_kernel<<<(N_EDGES + EPB - 1) / EPB, 256, 0, stream>>>(src, dst, gcur, gbuck);
    place_kernel<<<NB, 256, 0, stream>>>(gcur, gbuck, rowptr, esrc);

    const int agg_grid = (N_NODES + 3) / 4;

    for (int i = 0; i < N_LAYERS; ++i) {
        agg_kernel<<<agg_grid, 256, 0, stream>>>((const unsigned*)Bh, rowptr, esrc,
                                                 (unsigned*)Bz);
        mlp_kernel<<<256, 512, 0, stream>>>(Bz,
                                            Wt + (size_t)i * CH * CH,
                                            Wt + (size_t)(3 + i) * CH * CH,
                                            shift + i * CH,
                                            scale + (3 + i) * CH,
                                            shift + (3 + i) * CH,
                                            Bh);
    }

    pool_kernel<<<N_GRAPHS * NSPLIT, 64, 0, stream>>>((const unsigned*)Bh, starts, pooled);
    cls_kernel<<<(N_GRAPHS * OUT_CH + 255) / 256, 256, 0, stream>>>(pooled, Wc, bc, out);
}

// Round 14
// 270.509 us; speedup vs baseline: 1.7326x; 1.1797x over previous
//
#include <hip/hip_runtime.h>

#define N_NODES 50000
#define N_EDGES 800000
#define CH 128
#define N_GRAPHS 128
#define N_LAYERS 3
#define OUT_CH 16
#define BN_EPS 1e-5f
#define NSPLIT 16
#define NB 196            // dst>>8 buckets (256 dsts each)
#define BCAP 4608
#define EPB 4096
#define NTILES (N_NODES / 16)      // 3125 exact
#define SSTRIDE 20
// setup_kernel block partition
#define CB 6250            // cast blocks (1.6M float4 / 256)
#define SB 196             // starts blocks
#define PB 388             // prep blocks

typedef unsigned short ushort_t;
typedef __attribute__((ext_vector_type(8))) short bf16x8;
typedef __attribute__((ext_vector_type(4))) float f32x4;

__device__ inline ushort_t f2b(float f) {
    unsigned u = __float_as_uint(f);
    unsigned r = (u + 0x7fffu + ((u >> 16) & 1u)) >> 16;
    return (ushort_t)r;
}
__device__ inline float b2f(ushort_t b) { return __uint_as_float((unsigned)b << 16); }
__device__ inline float blo(unsigned u) { return __uint_as_float(u << 16); }
__device__ inline float bhi(unsigned u) { return __uint_as_float(u & 0xffff0000u); }

// ---------------- merged setup: cast | starts+pooled-zero | weight/epilogue prep ----------
__global__ __launch_bounds__(256) void setup_kernel(
    const float4* __restrict__ x, ushort4* __restrict__ xb, int* __restrict__ gcur,
    const int* __restrict__ batch, int* __restrict__ starts, float* __restrict__ pooled,
    const float* __restrict__ W1, const float* __restrict__ W2, ushort_t* __restrict__ Wt,
    const float* __restrict__ b1, const float* __restrict__ b2,
    const float* __restrict__ gamma, const float* __restrict__ beta,
    const float* __restrict__ mean, const float* __restrict__ var,
    float* __restrict__ scale, float* __restrict__ shift) {
    int bid = blockIdx.x, t = threadIdx.x;
    if (bid < CB) {
        // ---- cast fp32 -> bf16 flat [N][128]; zero gcur ----
        int i = bid * 256 + t;
        if (i < NB) gcur[i] = 0;
        float4 v = x[i];               // CB*256 == n4 exactly
        ushort4 o;
        o.x = f2b(v.x); o.y = f2b(v.y); o.z = f2b(v.z); o.w = f2b(v.w);
        xb[i] = o;
    } else if (bid < CB + SB) {
        // ---- graph starts from sorted batch; zero pooled ----
        int i = (bid - CB) * 256 + t;
        if (i < N_GRAPHS * CH) pooled[i] = 0.f;
        if (i >= N_NODES) return;
        int b = batch[i];
        if (i == 0) {
            for (int g = 0; g <= b; ++g) starts[g] = 0;
        } else {
            int pb = batch[i - 1];
            for (int g = pb + 1; g <= b; ++g) starts[g] = i;
        }
        if (i == N_NODES - 1) {
            for (int g = b + 1; g <= N_GRAPHS; ++g) starts[g] = N_NODES;
        }
    } else {
        // ---- weight fragments [ct][ks][lane][j] + scale/shift ----
        int i = (bid - CB - SB) * 256 + t;
        if (i < 6 * CH * CH) {
            int mat = i >> 14, r = i & 16383;
            int j = r & 7, bb = r >> 3;
            int lane = bb & 63, cs = bb >> 6;
            int ct = cs >> 2, ks = cs & 3;
            int n = ct * 16 + (lane & 15);
            int k = ks * 32 + (lane >> 4) * 8 + j;
            const float* Wsrc = (mat < 3) ? (W1 + (size_t)mat * CH * CH)
                                          : (W2 + (size_t)(mat - 3) * CH * CH);
            Wt[i] = f2b(Wsrc[k * CH + n]);
        } else {
            int e = i - 6 * CH * CH;
            if (e >= 6 * CH) return;
            int mat = e / CH, c = e % CH;
            if (mat < 3) {
                scale[e] = 1.f;
                shift[e] = b1[mat * CH + c];
            } else {
                int l = mat - 3;
                float inv = gamma[l * CH + c] * rsqrtf(var[l * CH + c] + BN_EPS);
                scale[e] = inv;
                shift[e] = (b2[l * CH + c] - mean[l * CH + c]) * inv + beta[l * CH + c];
            }
        }
    }
}

// ---------------- edge binning: pack = src | (dst&255)<<16, bucket = dst>>8 ----------------
__global__ __launch_bounds__(256) void bin_kernel(const int* __restrict__ src,
                                                  const int* __restrict__ dst,
                                                  int* __restrict__ gcur,
                                                  unsigned* __restrict__ gbuck) {
    __shared__ int lcnt[256];
    __shared__ int lpref[256];
    __shared__ int lpos[NB];
    __shared__ int lbase[NB];
    __shared__ unsigned stage[EPB];
    __shared__ unsigned char sbk[EPB];
    int t = threadIdx.x;
    int e0 = blockIdx.x * EPB;
    int nloc = N_EDGES - e0; if (nloc > EPB) nloc = EPB;

    lcnt[t] = 0;
    __syncthreads();

    int2 ed[16];
    #pragma unroll
    for (int j = 0; j < 16; ++j) {
        int i = j * 256 + t;
        if (i < nloc) {
            ed[j].x = src[e0 + i];
            ed[j].y = dst[e0 + i];
            atomicAdd(&lcnt[ed[j].y >> 8], 1);
        } else ed[j].y = -1;
    }
    __syncthreads();
    int v = lcnt[t];
    lpref[t] = v;
    __syncthreads();
    for (int off = 1; off < 256; off <<= 1) {
        int y = (t >= off) ? lpref[t - off] : 0;
        __syncthreads();
        lpref[t] += y;
        __syncthreads();
    }
    int excl = lpref[t] - v;
    __syncthreads();
    lpref[t] = excl;
    if (t < NB) {
        lpos[t] = excl;
        lbase[t] = atomicAdd(&gcur[t], v);
    }
    __syncthreads();
    #pragma unroll
    for (int j = 0; j < 16; ++j) {
        if (ed[j].y >= 0) {
            int b = ed[j].y >> 8;
            int slot = atomicAdd(&lpos[b], 1);
            stage[slot] = (unsigned)ed[j].x | ((unsigned)(ed[j].y & 255) << 16);
            sbk[slot] = (unsigned char)b;
        }
    }
    __syncthreads();
    for (int i = t; i < nloc; i += 256) {
        int b = sbk[i];
        gbuck[(size_t)b * BCAP + lbase[b] + (i - lpref[b])] = stage[i];
    }
}

// ---------------- per-bucket sort to CSR slots; inline bucket scan; writes rowptr ----------
__global__ __launch_bounds__(256) void place_kernel(const int* __restrict__ gcur,
                                                    const unsigned* __restrict__ gbuck,
                                                    int* __restrict__ rowptr,
                                                    ushort_t* __restrict__ esrc) {
    __shared__ ushort_t ssrc[BCAP];
    __shared__ unsigned char sd[BCAP];
    __shared__ int outS[BCAP];
    __shared__ int cnt[256], pref[256], cur[256];
    __shared__ int sscan[256];
    int b = blockIdx.x, t = threadIdx.x;
    // inline exclusive scan over all bucket sizes -> this bucket's base
    int gv = (t < NB) ? gcur[t] : 0;
    sscan[t] = gv;
    cnt[t] = 0;
    __syncthreads();
    for (int off = 1; off < 256; off <<= 1) {
        int y = (t >= off) ? sscan[t - off] : 0;
        __syncthreads();
        sscan[t] += y;
        __syncthreads();
    }
    int nb = gcur[b];
    int base = sscan[b] - nb;   // exclusive prefix
    for (int i = t; i < nb; i += 256) {
        unsigned p = gbuck[(size_t)b * BCAP + i];
        ssrc[i] = (ushort_t)(p & 0xffffu);
        int dl = (p >> 16) & 0xff;
        sd[i] = (unsigned char)dl;
        atomicAdd(&cnt[dl], 1);
    }
    __syncthreads();
    int v = cnt[t];
    pref[t] = v;
    __syncthreads();
    for (int off = 1; off < 256; off <<= 1) {
        int y = (t >= off) ? pref[t - off] : 0;
        __syncthreads();
        pref[t] += y;
        __syncthreads();
    }
    int excl = pref[t] - v;
    __syncthreads();
    pref[t] = excl;
    cur[t] = 0;
    int idx = (b << 8) + t;
    if (idx < N_NODES) rowptr[idx] = base + excl;
    if (b == NB - 1 && t == 0) rowptr[N_NODES] = N_EDGES;
    __syncthreads();
    for (int i = t; i < nb; i += 256) {
        int dl = sd[i];
        int p = pref[dl] + atomicAdd(&cur[dl], 1);
        outS[p] = ssrc[i];
    }
    __syncthreads();
    for (int i = t; i < nb; i += 256)
        esrc[base + i] = (ushort_t)outS[i];
}

// ---------------- aggregation: pull, wave/node, 16-deep gather unroll, u16 indices --------
__global__ __launch_bounds__(256) void agg_kernel(const unsigned* __restrict__ h2,
                                                  const int* __restrict__ rowptr,
                                                  const ushort_t* __restrict__ esrc,
                                                  unsigned* __restrict__ z2) {
    int wid = (blockIdx.x * 256 + threadIdx.x) >> 6;
    int lane = threadIdx.x & 63;
    if (wid >= N_NODES) return;
    unsigned self = h2[(size_t)wid * 64 + lane];
    float ax = blo(self), ay = bhi(self);
    int e = rowptr[wid], end = rowptr[wid + 1];
    for (; e + 16 <= end; e += 16) {
        unsigned u[16];
        #pragma unroll
        for (int j = 0; j < 16; ++j) {
            int s = esrc[e + j];
            u[j] = h2[(size_t)s * 64 + lane];
        }
        #pragma unroll
        for (int j = 0; j < 16; ++j) { ax += blo(u[j]); ay += bhi(u[j]); }
    }
    for (; e + 8 <= end; e += 8) {
        unsigned u[8];
        #pragma unroll
        for (int j = 0; j < 8; ++j) {
            int s = esrc[e + j];
            u[j] = h2[(size_t)s * 64 + lane];
        }
        #pragma unroll
        for (int j = 0; j < 8; ++j) { ax += blo(u[j]); ay += bhi(u[j]); }
    }
    for (; e + 4 <= end; e += 4) {
        unsigned u[4];
        #pragma unroll
        for (int j = 0; j < 4; ++j) {
            int s = esrc[e + j];
            u[j] = h2[(size_t)s * 64 + lane];
        }
        #pragma unroll
        for (int j = 0; j < 4; ++j) { ax += blo(u[j]); ay += bhi(u[j]); }
    }
    for (; e < end; ++e) {
        unsigned u = h2[(size_t)esrc[e] * 64 + lane];
        ax += blo(u); ay += bhi(u);
    }
    z2[(size_t)wid * 64 + lane] = ((unsigned)f2b(ay) << 16) | (unsigned)f2b(ax);
}

// ---------------- fused MLP (R8 conflict-free form) ----------------
__global__ __launch_bounds__(512) void mlp_kernel(const ushort_t* __restrict__ A,
                                                  const ushort_t* __restrict__ Wf1,
                                                  const ushort_t* __restrict__ Wf2,
                                                  const float* __restrict__ shift1,
                                                  const float* __restrict__ scale2,
                                                  const float* __restrict__ shift2,
                                                  ushort_t* __restrict__ Out) {
    __shared__ ushort_t sW1[CH * CH];
    __shared__ ushort_t sW2[CH * CH];
    __shared__ ushort_t sS[8][CH * SSTRIDE];

    int t = threadIdx.x;
    int wave = t >> 6, lane = t & 63;
    int quad = lane >> 4, l16 = lane & 15;

    {
        const uint4* g1 = (const uint4*)Wf1;
        const uint4* g2 = (const uint4*)Wf2;
        uint4* s1 = (uint4*)sW1;
        uint4* s2 = (uint4*)sW2;
        for (int i = t; i < 2048; i += 512) { s1[i] = g1[i]; s2[i] = g2[i]; }
    }
    __syncthreads();

    const bf16x8* w1f = (const bf16x8*)sW1;
    const bf16x8* w2f = (const bf16x8*)sW2;
    int wg = blockIdx.x * 8 + wave;

    for (int it = 0; it < 2; ++it) {
        int tile = wg + 2048 * it;
        if (tile >= NTILES) break;
        int arow = tile * 16 + l16;

        bf16x8 af[4];
        #pragma unroll
        for (int ks = 0; ks < 4; ++ks)
            af[ks] = *(const bf16x8*)(A + (size_t)arow * CH + ks * 32 + quad * 8);

        f32x4 acc[8];
        #pragma unroll
        for (int ct = 0; ct < 8; ++ct) acc[ct] = (f32x4){0.f, 0.f, 0.f, 0.f};
        #pragma unroll
        for (int ct = 0; ct < 8; ++ct)
            #pragma unroll
            for (int ks = 0; ks < 4; ++ks)
                acc[ct] = __builtin_amdgcn_mfma_f32_16x16x32_bf16(
                    af[ks], w1f[(ct * 4 + ks) * 64 + lane], acc[ct], 0, 0, 0);

        #pragma unroll
        for (int ct = 0; ct < 8; ++ct) {
            int k = ct * 16 + l16;
            float sh = shift1[k];
            uint2 p;
            p.x = ((unsigned)f2b(fmaxf(acc[ct][1] + sh, 0.f)) << 16)
                |  (unsigned)f2b(fmaxf(acc[ct][0] + sh, 0.f));
            p.y = ((unsigned)f2b(fmaxf(acc[ct][3] + sh, 0.f)) << 16)
                |  (unsigned)f2b(fmaxf(acc[ct][2] + sh, 0.f));
            *(uint2*)&sS[wave][k * SSTRIDE + quad * 4] = p;
        }

        bf16x8 af2[4];
        #pragma unroll
        for (int ks = 0; ks < 4; ++ks)
            #pragma unroll
            for (int j = 0; j < 8; ++j)
                af2[ks][j] = (short)sS[wave][(ks * 32 + quad * 8 + j) * SSTRIDE + l16];

        f32x4 acc2[8];
        #pragma unroll
        for (int ct = 0; ct < 8; ++ct) acc2[ct] = (f32x4){0.f, 0.f, 0.f, 0.f};
        #pragma unroll
        for (int ct = 0; ct < 8; ++ct)
            #pragma unroll
            for (int ks = 0; ks < 4; ++ks)
                acc2[ct] = __builtin_amdgcn_mfma_f32_16x16x32_bf16(
                    af2[ks], w2f[(ct * 4 + ks) * 64 + lane], acc2[ct], 0, 0, 0);

        int row0 = tile * 16;
        #pragma unroll
        for (int ct = 0; ct < 8; ++ct) {
            int col = ct * 16 + l16;
            float sc = scale2[col], sh = shift2[col];
            #pragma unroll
            for (int r = 0; r < 4; ++r) {
                int row = row0 + quad * 4 + r;
                Out[(size_t)row * CH + col] = f2b(fmaxf(acc2[ct][r] * sc + sh, 0.f));
            }
        }
    }
}

// ---------------- pooling (dword reads, 16 splits) + classifier ----------------
__global__ __launch_bounds__(64) void pool_kernel(const unsigned* __restrict__ h2,
                                                  const int* __restrict__ starts,
                                                  float* __restrict__ pooled) {
    int g = blockIdx.x >> 4, s = blockIdx.x & 15;
    int c = threadIdx.x;
    int beg = starts[g], end = starts[g + 1];
    float s0 = 0.f, s1 = 0.f;
    for (int n = beg + s; n < end; n += NSPLIT) {
        unsigned u = h2[(size_t)n * 64 + c];
        s0 += blo(u); s1 += bhi(u);
    }
    atomicAdd(&pooled[g * CH + 2 * c], s0);
    atomicAdd(&pooled[g * CH + 2 * c + 1], s1);
}

__global__ __launch_bounds__(256) void cls_kernel(const float* __restrict__ pooled,
                                                  const float* __restrict__ Wc,
                                                  const float* __restrict__ bc,
                                                  float* __restrict__ out) {
    int i = blockIdx.x * blockDim.x + threadIdx.x;
    if (i >= N_GRAPHS * OUT_CH) return;
    int g = i / OUT_CH, o = i % OUT_CH;
    float s = bc[o];
    for (int k = 0; k < CH; ++k) s += pooled[g * CH + k] * Wc[k * OUT_CH + o];
    out[i] = s;
}

// ---------------- launch ----------------
extern "C" void kernel_launch(void* const* d_in, const int* in_sizes, int n_in,
                              void* d_out, int out_size, void* d_ws, size_t ws_size,
                              hipStream_t stream) {
    const float* x     = (const float*)d_in[0];
    const int*   eidx  = (const int*)d_in[1];
    const int*   batch = (const int*)d_in[2];
    const float* W1    = (const float*)d_in[3];
    const float* b1    = (const float*)d_in[4];
    const float* W2    = (const float*)d_in[5];
    const float* b2    = (const float*)d_in[6];
    const float* gamma = (const float*)d_in[7];
    const float* beta  = (const float*)d_in[8];
    const float* mean  = (const float*)d_in[9];
    const float* var   = (const float*)d_in[10];
    const float* Wc    = (const float*)d_in[11];
    const float* bc    = (const float*)d_in[12];
    float* out = (float*)d_out;

    const int* src = eidx;
    const int* dst = eidx + N_EDGES;

    char* w = (char*)d_ws;
    size_t off = 0;
    auto alloc = [&](size_t bytes) { void* p = w + off; off += (bytes + 255) & ~(size_t)255; return p; };
    int*      gcur   = (int*)alloc(NB * 4);
    unsigned* gbuck  = (unsigned*)alloc((size_t)NB * BCAP * 4);
    int*      rowptr = (int*)alloc((N_NODES + 1) * 4);
    ushort_t* esrc   = (ushort_t*)alloc(N_EDGES * 2);
    int*      starts = (int*)alloc((N_GRAPHS + 1) * 4);
    ushort_t* Bh     = (ushort_t*)alloc((size_t)N_NODES * CH * 2);
    ushort_t* Bz     = (ushort_t*)alloc((size_t)N_NODES * CH * 2);
    ushort_t* Wt     = (ushort_t*)alloc((size_t)6 * CH * CH * 2);
    float*    scale  = (float*)alloc(6 * CH * 4);
    float*    shift  = (float*)alloc(6 * CH * 4);
    float*    pooled = (float*)alloc(N_GRAPHS * CH * 4);
    (void)ws_size; (void)n_in; (void)in_sizes; (void)out_size;

    setup_kernel<<<CB + SB + PB, 256, 0, stream>>>(
        (const float4*)x, (ushort4*)Bh, gcur,
        batch, starts, pooled,
        W1, W2, Wt, b1, b2, gamma, beta, mean, var, scale, shift);
    bin_kernel<<<(N_EDGES + EPB - 1) / EPB, 256, 0, stream>>>(src, dst, gcur, gbuck);
    place_kernel<<<NB, 256, 0, stream>>>(gcur, gbuck, rowptr, esrc);

    const int agg_grid = (N_NODES + 3) / 4;

    for (int i = 0; i < N_LAYERS; ++i) {
        agg_kernel<<<agg_grid, 256, 0, stream>>>((const unsigned*)Bh, rowptr, esrc,
                                                 (unsigned*)Bz);
        mlp_kernel<<<256, 512, 0, stream>>>(Bz,
                                            Wt + (size_t)i * CH * CH,
                                            Wt + (size_t)(3 + i) * CH * CH,
                                            shift + i * CH,
                                            scale + (3 + i) * CH,
                                            shift + (3 + i) * CH,
                                            Bh);
    }

    pool_kernel<<<N_GRAPHS * NSPLIT, 64, 0, stream>>>((const unsigned*)Bh, starts, pooled);
    cls_kernel<<<(N_GRAPHS * OUT_CH + 255) / 256, 256, 0, stream>>>(pooled, Wc, bc, out);
}